// Round 10
// baseline (444.299 us; speedup 1.0000x reference)
//
#include <hip/hip_runtime.h>
#include <hip/hip_bf16.h>
#include <cstddef>

#define N_NODES 100000
#define E_EDGES 1600000
#define TOT_EDGES (E_EDGES + N_NODES)
#define NEG_SLOPE 0.2f
#define BN_EPS 1e-5f
#define NBKT ((N_NODES + 255) / 256)   /* 391 coarse buckets (dst>>8) */
#define NBA 512                        /* blocks in CSR pass A */

typedef __attribute__((ext_vector_type(8))) short short8;
typedef __attribute__((ext_vector_type(4))) float f32x4;
typedef __attribute__((ext_vector_type(2))) float f32x2;
typedef __attribute__((ext_vector_type(4))) int int32x4;
typedef __attribute__((ext_vector_type(2))) int int32x2;

#if defined(__has_builtin)
#if __has_builtin(__builtin_amdgcn_make_buffer_rsrc) && __has_builtin(__builtin_amdgcn_raw_buffer_load_b128)
#define HAVE_BUFRSRC 1
#endif
#if __has_builtin(__builtin_amdgcn_make_buffer_rsrc) && __has_builtin(__builtin_amdgcn_raw_buffer_load_b64)
#define HAVE_BUF64 1
#endif
#endif

__device__ __forceinline__ unsigned short f2bf(float f) {
    union { float f; unsigned u; } c; c.f = f;
    unsigned u = c.u;
    u += 0x7fffu + ((u >> 16) & 1u);
    return (unsigned short)(u >> 16);
}
__device__ __forceinline__ float bf2f(unsigned short h) {
    union { unsigned u; float f; } c; c.u = ((unsigned)h) << 16;
    return c.f;
}
// f16 helpers (h1/h3 gather payloads are f16: better mantissa than bf16 in
// this range AND (float)h * w + acc fuses to v_fma_mix_f32)
__device__ __forceinline__ unsigned short f2h(float f) {
    union { _Float16 h; unsigned short u; } c; c.h = (_Float16)f; return c.u;
}
__device__ __forceinline__ float lrelu(float t) {
    return (t > 0.f) ? t : NEG_SLOPE * t;
}
// fast tanh: 1 - 2/(e^{2x}+1). |err| ~1e-6 absolute; saturates correctly.
__device__ __forceinline__ float tanh_fast(float x) {
    float e = __expf(2.f * x);
    return 1.f - 2.f / (e + 1.f);
}
// HW fp8 (e4m3 on gfx950) pack/unpack via inline asm — self-consistent
// roundtrip (encode and decode use the same HW interpretation).
__device__ __forceinline__ unsigned short pk_fp8(float a, float b) {
    unsigned v;
    asm volatile("v_cvt_pk_fp8_f32 %0, %1, %2" : "=v"(v) : "v"(a), "v"(b));
    return (unsigned short)v;
}
__device__ __forceinline__ f32x2 unpk_fp8(unsigned u) {
    f32x2 r;
    asm volatile("v_cvt_pk_f32_fp8 %0, %1" : "=v"(r) : "v"(u));
    return r;
}

// ---------------------------------------------------------------------------
// DPP wave-64 sum (VALU pipe, ~6 dependent adds). Result valid in LANE 63.
// bound_ctrl=true: invalid source lanes contribute 0 (correct for add).
// ---------------------------------------------------------------------------
__device__ __forceinline__ float wave_sum63(float x) {
    x += __int_as_float(__builtin_amdgcn_update_dpp(0, __float_as_int(x), 0x111, 0xf, 0xf, true)); // row_shr:1
    x += __int_as_float(__builtin_amdgcn_update_dpp(0, __float_as_int(x), 0x112, 0xf, 0xf, true)); // row_shr:2
    x += __int_as_float(__builtin_amdgcn_update_dpp(0, __float_as_int(x), 0x114, 0xf, 0xf, true)); // row_shr:4
    x += __int_as_float(__builtin_amdgcn_update_dpp(0, __float_as_int(x), 0x118, 0xf, 0xf, true)); // row_shr:8
    x += __int_as_float(__builtin_amdgcn_update_dpp(0, __float_as_int(x), 0x142, 0xf, 0xf, true)); // row_bcast:15
    x += __int_as_float(__builtin_amdgcn_update_dpp(0, __float_as_int(x), 0x143, 0xf, 0xf, true)); // row_bcast:31
    return x;
}
__device__ __forceinline__ float wave_sum_bcast(float x) {
    return __int_as_float(__builtin_amdgcn_readlane(__float_as_int(wave_sum63(x)), 63));
}

// ---------------------------------------------------------------------------
// CSR build — two-level LDS counting sort, ZERO global atomics.
// ---------------------------------------------------------------------------

__global__ __launch_bounds__(256) void csr_hist(const int* __restrict__ ei,
                                                int* __restrict__ bh) {
    __shared__ int h[NBKT];
    int t = threadIdx.x;
    for (int b = t; b < NBKT; b += 256) h[b] = 0;
    __syncthreads();
    int idx = blockIdx.x * 256 + t;
    const int stride = NBA * 256;
    for (int e = idx; e < TOT_EDGES; e += stride) {
        int d = (e < E_EDGES) ? ei[E_EDGES + e] : (e - E_EDGES);
        atomicAdd(&h[((unsigned)d) >> 8], 1);
    }
    __syncthreads();
    for (int b = t; b < NBKT; b += 256) bh[blockIdx.x * NBKT + b] = h[b];
}

// per-bin exclusive scan over the NBA block histograms (one block per bin)
__global__ __launch_bounds__(512) void csr_scan_blocks(int* __restrict__ bh,
                                                       int* __restrict__ totals) {
    __shared__ int s[NBA];
    int t = threadIdx.x, bin = blockIdx.x;
    int v = bh[t * NBKT + bin];
    s[t] = v;
    __syncthreads();
    for (int off = 1; off < NBA; off <<= 1) {
        int y = (t >= off) ? s[t - off] : 0;
        __syncthreads();
        s[t] += y;
        __syncthreads();
    }
    bh[t * NBKT + bin] = s[t] - v;          // exclusive offset for block t
    if (t == NBA - 1) totals[bin] = s[t];   // bucket total
}

// exclusive scan over bucket totals -> bucket start positions
__global__ __launch_bounds__(512) void csr_scan_buckets(const int* __restrict__ totals,
                                                        int* __restrict__ starts) {
    __shared__ int s[512];
    int t = threadIdx.x;
    int v = (t < NBKT) ? totals[t] : 0;
    s[t] = v;
    __syncthreads();
    for (int off = 1; off < 512; off <<= 1) {
        int y = (t >= off) ? s[t - off] : 0;
        __syncthreads();
        s[t] += y;
        __syncthreads();
    }
    if (t < NBKT) starts[t] = s[t] - v;
    if (t == 0) starts[NBKT] = TOT_EDGES;
}

__global__ __launch_bounds__(256) void csr_scatter(const int* __restrict__ ei,
                                                   const int* __restrict__ bh,
                                                   const int* __restrict__ starts,
                                                   int* __restrict__ pairs) {
    __shared__ int wp[NBKT];
    int t = threadIdx.x;
    for (int b = t; b < NBKT; b += 256)
        wp[b] = starts[b] + bh[blockIdx.x * NBKT + b];
    __syncthreads();
    int idx = blockIdx.x * 256 + t;
    const int stride = NBA * 256;
    for (int e = idx; e < TOT_EDGES; e += stride) {
        int s, d;
        if (e < E_EDGES) { s = ei[e]; d = ei[E_EDGES + e]; }
        else             { s = e - E_EDGES; d = s; }
        int pos = atomicAdd(&wp[((unsigned)d) >> 8], 1);
        pairs[pos] = s | ((d & 255) << 20);
    }
}

__global__ __launch_bounds__(256) void csr_build(const int* __restrict__ pairs,
                                                 const int* __restrict__ starts,
                                                 int* __restrict__ row_ptr,
                                                 int* __restrict__ src_sorted) {
    __shared__ int nh[256];
    __shared__ int sc[256];
    __shared__ int wp[256];
    int k = blockIdx.x, t = threadIdx.x;
    int bs = starts[k], be = starts[k + 1];
    nh[t] = 0;
    __syncthreads();
    for (int i = bs + t; i < be; i += 256)
        atomicAdd(&nh[((unsigned)pairs[i]) >> 20], 1);
    __syncthreads();
    int v = nh[t];
    sc[t] = v;
    __syncthreads();
    for (int off = 1; off < 256; off <<= 1) {
        int y = (t >= off) ? sc[t - off] : 0;
        __syncthreads();
        sc[t] += y;
        __syncthreads();
    }
    int excl = sc[t] - v;
    int node = k * 256 + t;
    if (node <= N_NODES) row_ptr[node] = bs + excl;  // row_ptr[N] from last bucket
    wp[t] = bs + excl;
    __syncthreads();
    for (int i = bs + t; i < be; i += 256) {
        unsigned p = (unsigned)pairs[i];
        int pos = atomicAdd(&wp[p >> 20], 1);
        src_sorted[pos] = (int)(p & 0xFFFFFu);
    }
}

// weight transposes + alpha vectors + folded BN2 (S,T), one launch
__global__ __launch_bounds__(256) void wprep_all(
    const float* __restrict__ w1, const float* __restrict__ w2, const float* __restrict__ w3,
    const float* __restrict__ as1, const float* __restrict__ ad1,
    const float* __restrict__ as2, const float* __restrict__ ad2,
    const float* __restrict__ as3, const float* __restrict__ ad3,
    const float* __restrict__ b2a, const float* __restrict__ g2a,
    const float* __restrict__ be2a, const float* __restrict__ rm2a,
    const float* __restrict__ rv2a,
    unsigned short* __restrict__ w1th, unsigned short* __restrict__ w1tl,
    unsigned short* __restrict__ w2th, unsigned short* __restrict__ w2tl,
    unsigned short* __restrict__ w3th, unsigned short* __restrict__ w3tl,
    unsigned short* __restrict__ ab1h, unsigned short* __restrict__ ab1l,
    unsigned short* __restrict__ ab3h, unsigned short* __restrict__ ab3l,
    float* __restrict__ ws2f, float* __restrict__ wd2f,
    float* __restrict__ bn2S, float* __restrict__ bn2T) {
    const int T1 = 128 * 128, T2 = 256 * 128, T3 = 48 * 256;
    const int W = T1 + T2 + T3;
    int idx = blockIdx.x * 256 + threadIdx.x;
    if (idx < W) {
        float v; unsigned short* th; unsigned short* tl; int o;
        if (idx < T1) {
            int n = idx / 128, k = idx % 128;
            v = w1[k * 128 + n]; th = w1th; tl = w1tl; o = idx;
        } else if (idx < T1 + T2) {
            int i = idx - T1; int n = i / 128, k = i % 128;
            v = w2[k * 256 + n]; th = w2th; tl = w2tl; o = i;
        } else {
            int i = idx - T1 - T2; int n = i / 256, k = i % 256;
            v = (n < 40) ? w3[k * 40 + n] : 0.f; th = w3th; tl = w3tl; o = i;
        }
        unsigned short h = f2bf(v);
        th[o] = h;
        tl[o] = f2bf(v - bf2f(h));
        return;
    }
    int j = idx - W;
    if (j < 2048) {
        int r = j / 128, k = j % 128;
        float v = 0.f;
        if (r < 2) {
            const float* a = r ? ad1 : as1;
            const float* wr = w1 + (size_t)k * 128;
            for (int n = 0; n < 128; n++) v += wr[n] * a[n];
        }
        unsigned short h = f2bf(v);
        ab1h[j] = h; ab1l[j] = f2bf(v - bf2f(h));
    } else if (j < 2048 + 4096) {
        int i = j - 2048; int r = i / 256, k = i % 256;
        float v = 0.f;
        if (r < 2) {
            const float* a = r ? ad3 : as3;
            const float* wr = w3 + (size_t)k * 40;
            for (int n = 0; n < 40; n++) v += wr[n] * a[n];
        }
        unsigned short h = f2bf(v);
        ab3h[i] = h; ab3l[i] = f2bf(v - bf2f(h));
    } else if (j < 2048 + 4096 + 256) {
        int i = j - 2048 - 4096; int r = i / 128, k = i % 128;
        const float* a = r ? ad2 : as2;
        const float* wr = w2 + (size_t)k * 256;
        float v = 0.f;
        for (int n = 0; n < 256; n++) v += wr[n] * a[n];
        if (r == 0) ws2f[k] = v; else wd2f[k] = v;
    } else if (j < 2048 + 4096 + 256 + 256) {
        int i = j - 2048 - 4096 - 256;   // col 0..255
        float S = rsqrtf(rv2a[i] + BN_EPS) * g2a[i];
        bn2S[i] = S;
        bn2T[i] = (b2a[i] - rm2a[i]) * S + be2a[i];
    }
}

// ---------------------------------------------------------------------------
// Split-bf16 MFMA GEMM (used for layer-1 only now).
// AF32:  A read directly from row-major f32 (stride K), split hi/lo INLINE.
// ---------------------------------------------------------------------------
template<int K, int NTILES, int MWAVES, int NWAVES, int NACT, bool ASPLIT, bool ALPHA, bool BNT, bool CFRAG, bool CHALF, bool AF32>
__global__ __launch_bounds__(256) void mfma_gemm(
    const unsigned short* __restrict__ Ahi, const unsigned short* __restrict__ Alo,
    const unsigned short* __restrict__ BThi, const unsigned short* __restrict__ BTlo,
    const unsigned short* __restrict__ ABh, const unsigned short* __restrict__ ABl,
    unsigned short* __restrict__ Chi, int ldc,
    const float* __restrict__ bias, const float* __restrict__ gamma,
    const float* __restrict__ beta, const float* __restrict__ rmean,
    const float* __restrict__ rvar,
    float* __restrict__ asrc, float* __restrict__ adst, int M)
{
    int lane = threadIdx.x & 63;
    int wave = threadIdx.x >> 6;
    int quad = lane >> 4;
    int l16  = lane & 15;
    long mbase = (long)blockIdx.x * (64 * MWAVES) + (long)(wave / NWAVES) * 64;
    int n0 = ((wave % NWAVES) + blockIdx.y * NWAVES) * (NTILES * 16);
    bool aw = ((wave % NWAVES) == 0) && (blockIdx.y == 0);
    const size_t CSTRIDE = (size_t)M * 32;  // fragment chunk stride (u16)

    size_t roff[4];
#pragma unroll
    for (int i = 0; i < 4; i++) {
        long r = mbase + i * 16 + l16;
        if (r > M - 1) r = M - 1;
        roff[i] = AF32 ? ((size_t)r * K + (size_t)(quad * 8))    // f32 units
                       : ((size_t)r * 32 + (size_t)(quad * 8));  // u16 units
    }
    const unsigned short* bh[NTILES]; const unsigned short* bl[NTILES];
#pragma unroll
    for (int j = 0; j < NTILES; j++) {
        long n = n0 + j * 16 + l16;
        bh[j] = BThi + n * K; bl[j] = BTlo + n * K;
    }
    const unsigned short* bah = nullptr; const unsigned short* bal = nullptr;
    if constexpr (ALPHA) { bah = ABh + (size_t)l16 * K; bal = ABl + (size_t)l16 * K; }
    const int ko = quad * 8;

    f32x4 acc[4][NTILES];
    f32x4 acca[4];
#pragma unroll
    for (int i = 0; i < 4; i++) {
        acca[i] = (f32x4){0.f, 0.f, 0.f, 0.f};
#pragma unroll
        for (int j = 0; j < NTILES; j++)
            acc[i][j] = (f32x4){0.f, 0.f, 0.f, 0.f};
    }

    for (int kc = 0; kc < K / 32; kc++) {
        const int k0 = kc * 32;
        short8 vah[4], vall[4], vbh[NTILES], vbl[NTILES];
#pragma unroll
        for (int i = 0; i < 4; i++) {
            if constexpr (AF32) {
                const float* xf = (const float*)Ahi;
                const float* pa = xf + roff[i] + kc * 32;
                f32x4 va = *(const f32x4*)pa;
                f32x4 vb = *(const f32x4*)(pa + 4);
#pragma unroll
                for (int q = 0; q < 8; q++) {
                    float v = (q < 4) ? va[q] : vb[q - 4];
                    unsigned short h = f2bf(v);
                    vah[i][q] = (short)h;
                    vall[i][q] = (short)f2bf(v - bf2f(h));
                }
            } else {
                const unsigned short* Ah = Ahi + (size_t)kc * CSTRIDE;
                vah[i] = *(const short8*)(Ah + roff[i]);
                if constexpr (ASPLIT) {
                    const unsigned short* Al = Alo + (size_t)kc * CSTRIDE;
                    vall[i] = *(const short8*)(Al + roff[i]);
                }
            }
        }
#pragma unroll
        for (int j = 0; j < NTILES; j++) {
            vbh[j] = *(const short8*)(bh[j] + k0 + ko);
            vbl[j] = *(const short8*)(bl[j] + k0 + ko);
        }
#pragma unroll
        for (int i = 0; i < 4; i++)
#pragma unroll
            for (int j = 0; j < NTILES; j++) {
                acc[i][j] = __builtin_amdgcn_mfma_f32_16x16x32_bf16(vah[i], vbh[j], acc[i][j], 0, 0, 0);
                acc[i][j] = __builtin_amdgcn_mfma_f32_16x16x32_bf16(vah[i], vbl[j], acc[i][j], 0, 0, 0);
                if constexpr (ASPLIT)
                    acc[i][j] = __builtin_amdgcn_mfma_f32_16x16x32_bf16(vall[i], vbh[j], acc[i][j], 0, 0, 0);
            }
        if constexpr (ALPHA) {
            if (aw) {
                short8 vbah = *(const short8*)(bah + k0 + ko);
                short8 vbal = *(const short8*)(bal + k0 + ko);
#pragma unroll
                for (int i = 0; i < 4; i++) {
                    acca[i] = __builtin_amdgcn_mfma_f32_16x16x32_bf16(vah[i], vbah, acca[i], 0, 0, 0);
                    acca[i] = __builtin_amdgcn_mfma_f32_16x16x32_bf16(vah[i], vbal, acca[i], 0, 0, 0);
                    if constexpr (ASPLIT)
                        acca[i] = __builtin_amdgcn_mfma_f32_16x16x32_bf16(vall[i], vbah, acca[i], 0, 0, 0);
                }
            }
        }
    }

#pragma unroll
    for (int i = 0; i < 4; i++)
#pragma unroll
        for (int j = 0; j < NTILES; j++) {
            int col = n0 + j * 16 + l16;
            float bb = 0.f, rs = 1.f, gg = 1.f, bt = 0.f, rm = 0.f;
            if constexpr (BNT) {
                bb = bias[col]; gg = gamma[col]; bt = beta[col];
                rm = rmean[col]; rs = rsqrtf(rvar[col] + BN_EPS);
            }
#pragma unroll
            for (int r = 0; r < 4; r++) {
                long row = mbase + i * 16 + quad * 4 + r;
                if (row < M && col < NACT) {
                    float v = acc[i][j][r];
                    if constexpr (BNT) v = tanh_fast((v + bb - rm) * rs * gg + bt);
                    if constexpr (CFRAG) {
                        Chi[(size_t)(col >> 5) * CSTRIDE + (size_t)row * 32 + (col & 31)] = f2bf(v);
                    } else {
                        Chi[row * ldc + col] = CHALF ? f2h(v) : f2bf(v);
                    }
                }
            }
        }
    if constexpr (ALPHA) {
        if (aw) {
#pragma unroll
            for (int i = 0; i < 4; i++)
#pragma unroll
                for (int r = 0; r < 4; r++) {
                    long row = mbase + i * 16 + quad * 4 + r;
                    if (row < M) {
                        float v = acca[i][r];
                        if (l16 == 0) asrc[row] = v;
                        else if (l16 == 1) adst[row] = v;
                    }
                }
        }
    }
}

// ---------------------------------------------------------------------------
// gemm23_fused v4: 32-row tiles, 256 threads / 4 waves, 20 KB LDS.
// Round-9 evidence: XCD-affinity was useless (FETCH unchanged — runtime must
// flush non-coherent per-XCD L2s between dispatches, so cross-kernel L2 reuse
// is impossible; g2 always comes from L3). The limiter is block-level
// concurrency: 40 KB LDS capped residency at 4 blocks/CU and the 1563-block
// grid left CUs serially eating L3 latency. v4 halves the tile (32 rows),
// doubling the grid to 3125 and allowing 8 blocks/CU (20 KB LDS) — L3
// latency now overlaps across blocks.
//   phase 1: wave w -> cols w*64..+63 (acc[2][4]); same 64 MFMAs/wave.
//   phase 2: 4 wave-tasks {3 col-tiles + alpha} over rows 0..31 (32 MFMAs).
// ---------------------------------------------------------------------------
__global__ __launch_bounds__(256) void gemm23_fused(
    const unsigned short* __restrict__ Ahi,   // g2hi fragment-major, K=128
    const unsigned short* __restrict__ B2h, const unsigned short* __restrict__ B2l,
    const float* __restrict__ bnS, const float* __restrict__ bnT,
    const unsigned short* __restrict__ B3h, const unsigned short* __restrict__ B3l,
    const unsigned short* __restrict__ AB3h, const unsigned short* __restrict__ AB3l,
    unsigned short* __restrict__ h3,          // f16, ldh=64, cols 0..47
    float* __restrict__ asrc, float* __restrict__ adst, int M)
{
    constexpr int LW = 40;                    // LDS row stride in u16
    __shared__ unsigned short o2l[8 * 32 * LW];   // 20 KB

    int lane = threadIdx.x & 63;
    int wave = threadIdx.x >> 6;              // 0..3
    int quad = lane >> 4;
    int l16  = lane & 15;
    long mbase = (long)blockIdx.x * 32;
    const size_t CSTRIDE = (size_t)M * 32;
    const int ko = quad * 8;

    // ---- phase 1: GEMM2 tile (32 x 256); wave w -> cols w*64..+63 ----
    size_t roff[2];
#pragma unroll
    for (int i = 0; i < 2; i++) {
        long r = mbase + i * 16 + l16;
        if (r > M - 1) r = M - 1;
        roff[i] = (size_t)r * 32 + (size_t)ko;
    }
    int n0 = wave * 64;
    const unsigned short* bh[4]; const unsigned short* bl[4];
#pragma unroll
    for (int j = 0; j < 4; j++) {
        long n = n0 + j * 16 + l16;
        bh[j] = B2h + n * 128; bl[j] = B2l + n * 128;
    }

    f32x4 acc[2][4];
#pragma unroll
    for (int i = 0; i < 2; i++)
#pragma unroll
        for (int j = 0; j < 4; j++)
            acc[i][j] = (f32x4){0.f, 0.f, 0.f, 0.f};

#pragma unroll
    for (int kc = 0; kc < 4; kc++) {
        const int k0 = kc * 32;
        const unsigned short* Ah = Ahi + (size_t)kc * CSTRIDE;
        short8 vah[2], vbh[4], vbl[4];
#pragma unroll
        for (int i = 0; i < 2; i++) vah[i] = *(const short8*)(Ah + roff[i]);
#pragma unroll
        for (int j = 0; j < 4; j++) {
            vbh[j] = *(const short8*)(bh[j] + k0 + ko);
            vbl[j] = *(const short8*)(bl[j] + k0 + ko);
        }
#pragma unroll
        for (int i = 0; i < 2; i++)
#pragma unroll
            for (int j = 0; j < 4; j++) {
                acc[i][j] = __builtin_amdgcn_mfma_f32_16x16x32_bf16(vah[i], vbh[j], acc[i][j], 0, 0, 0);
                acc[i][j] = __builtin_amdgcn_mfma_f32_16x16x32_bf16(vah[i], vbl[j], acc[i][j], 0, 0, 0);
            }
    }

    // folded-BN + tanh epilogue -> LDS (bf16, fragment layout, stride LW)
#pragma unroll
    for (int j = 0; j < 4; j++) {
        int col = n0 + j * 16 + l16;
        float S = bnS[col], T = bnT[col];
        int cbase = (col >> 5) * 32 * LW + (col & 31);
#pragma unroll
        for (int i = 0; i < 2; i++)
#pragma unroll
            for (int r = 0; r < 4; r++) {
                int li = i * 16 + quad * 4 + r;
                o2l[cbase + li * LW] = f2bf(tanh_fast(acc[i][j][r] * S + T));
            }
    }
    __syncthreads();

    // ---- phase 2: 4 wave-tasks = {3 col-tiles + alpha}, rows 0..31 ----
    int task = wave;                  // 0..2 = col tile, 3 = alpha
    int lrow0 = l16;                  // row-fragment i=0
    int lrow1 = 16 + l16;             // row-fragment i=1

    const unsigned short* p3h;
    const unsigned short* p3l;
    if (task < 3) {
        p3h = B3h + (size_t)(task * 16 + l16) * 256;
        p3l = B3l + (size_t)(task * 16 + l16) * 256;
    } else {
        p3h = AB3h + (size_t)l16 * 256;
        p3l = AB3l + (size_t)l16 * 256;
    }

    // kc-parity split: 4 chains x 8-deep
    f32x4 a3[2][2];
#pragma unroll
    for (int i = 0; i < 2; i++)
#pragma unroll
        for (int pp = 0; pp < 2; pp++)
            a3[i][pp] = (f32x4){0.f, 0.f, 0.f, 0.f};

#pragma unroll
    for (int kc = 0; kc < 8; kc++) {
        const int k0 = kc * 32;
        const int par = kc & 1;
        short8 a0 = *(const short8*)(o2l + (kc * 32 + lrow0) * LW + ko);
        short8 a1 = *(const short8*)(o2l + (kc * 32 + lrow1) * LW + ko);
        short8 vh = *(const short8*)(p3h + k0 + ko);
        short8 vl = *(const short8*)(p3l + k0 + ko);
        a3[0][par] = __builtin_amdgcn_mfma_f32_16x16x32_bf16(a0, vh, a3[0][par], 0, 0, 0);
        a3[0][par] = __builtin_amdgcn_mfma_f32_16x16x32_bf16(a0, vl, a3[0][par], 0, 0, 0);
        a3[1][par] = __builtin_amdgcn_mfma_f32_16x16x32_bf16(a1, vh, a3[1][par], 0, 0, 0);
        a3[1][par] = __builtin_amdgcn_mfma_f32_16x16x32_bf16(a1, vl, a3[1][par], 0, 0, 0);
    }
    f32x4 r3[2];
    r3[0] = a3[0][0] + a3[0][1];
    r3[1] = a3[1][0] + a3[1][1];

    if (task < 3) {
        int col = task * 16 + l16;
#pragma unroll
        for (int i = 0; i < 2; i++)
#pragma unroll
            for (int r = 0; r < 4; r++) {
                long row = mbase + i * 16 + quad * 4 + r;
                if (row < M) h3[(size_t)row * 64 + col] = f2h(r3[i][r]);
            }
    } else {
#pragma unroll
        for (int i = 0; i < 2; i++)
#pragma unroll
            for (int r = 0; r < 4; r++) {
                long row = mbase + i * 16 + quad * 4 + r;
                if (row < M) {
                    if (l16 == 0) asrc[row] = r3[i][r];
                    else if (l16 == 1) adst[row] = r3[i][r];
                }
            }
    }
}

// ---------------------------------------------------------------------------
// gat_agg_wide<MODE>: fused segment-softmax + wide gather-aggregate.
// (unchanged from round 4 — see comments there)
// ---------------------------------------------------------------------------
template<int MODE>
__global__ __launch_bounds__(256) void gat_agg_wide(
    const unsigned short* __restrict__ hsrc,
    const float* __restrict__ asrc, const float* __restrict__ adst,
    const int* __restrict__ row_ptr, const int* __restrict__ src_sorted,
    const float* __restrict__ bias, const float* __restrict__ gamma,
    const float* __restrict__ beta, const float* __restrict__ rmean,
    const float* __restrict__ rvar,
    const float* __restrict__ wsn, const float* __restrict__ wdn,
    unsigned short* __restrict__ ohi,
    float* __restrict__ outf,
    float* __restrict__ asrc_n, float* __restrict__ adst_n)
{
    constexpr int SH  = (MODE == 0) ? 8 : 7;     // log2(row bytes)
    constexpr int BPL = (MODE == 0) ? 16 : 8;    // bytes per lane
    constexpr int NF  = (MODE == 2) ? 4 : 8;     // feats accumulated per lane

    __shared__ __align__(16) float2 esw[4][64];      // transposed (src<<SH, w)
    __shared__ __align__(16) float red[4][4][132];   // [wave][sub][feat]

    int wave = threadIdx.x >> 6;
    int lane = threadIdx.x & 63;
    int node = blockIdx.x * 4 + wave;
    if (node >= N_NODES) return;

    int start = row_ptr[node];
    int end = row_ptr[node + 1];
    int deg = end - start;
    float ad = adst[node];
    int sub = lane >> 4;                       // which of 4 concurrent edges
    int foff = (lane & 15) * BPL;              // byte offset within row
    int tpos = (lane & 3) * 16 + (lane >> 2);  // transposed slot for lane's edge

#if defined(HAVE_BUFRSRC) && defined(HAVE_BUF64)
    auto rsrc = __builtin_amdgcn_make_buffer_rsrc((void*)hsrc, (short)0,
                                                  N_NODES << SH, 0x00020000);
#endif

    float acc[NF];
#pragma unroll
    for (int i = 0; i < NF; i++) acc[i] = 0.f;

    auto ld = [&](int vo) {
        if constexpr (MODE == 0) {
#if defined(HAVE_BUFRSRC) && defined(HAVE_BUF64)
            return __builtin_amdgcn_raw_buffer_load_b128(rsrc, vo, 0, 0);
#else
            return *reinterpret_cast<const int32x4*>(
                reinterpret_cast<const char*>(hsrc) + (unsigned)vo);
#endif
        } else {
#if defined(HAVE_BUFRSRC) && defined(HAVE_BUF64)
            return __builtin_amdgcn_raw_buffer_load_b64(rsrc, vo, 0, 0);
#else
            return *reinterpret_cast<const int32x2*>(
                reinterpret_cast<const char*>(hsrc) + (unsigned)vo);
#endif
        }
    };
    auto fmaN = [&](auto u, float ww) {
        if constexpr (MODE == 0) {
            union { decltype(u) v; unsigned w[4]; } c; c.v = u;
#pragma unroll
            for (int i = 0; i < 4; i++) {
                union { unsigned u; _Float16 h[2]; } t; t.u = c.w[i];
                acc[2 * i]     += ww * (float)t.h[0];   // v_fma_mix_f32
                acc[2 * i + 1] += ww * (float)t.h[1];
            }
        } else if constexpr (MODE == 1) {
            union { decltype(u) v; unsigned w[2]; } c; c.v = u;
#pragma unroll
            for (int i = 0; i < 2; i++) {
                f32x2 lo = unpk_fp8(c.w[i]);
                f32x2 hi = unpk_fp8(c.w[i] >> 16);
                acc[4 * i]     += ww * lo.x;
                acc[4 * i + 1] += ww * lo.y;
                acc[4 * i + 2] += ww * hi.x;
                acc[4 * i + 3] += ww * hi.y;
            }
        } else {
            union { decltype(u) v; unsigned w[2]; } c; c.v = u;
#pragma unroll
            for (int i = 0; i < 2; i++) {
                union { unsigned u; _Float16 h[2]; } t; t.u = c.w[i];
                acc[2 * i]     += ww * (float)t.h[0];
                acc[2 * i + 1] += ww * (float)t.h[1];
            }
        }
    };
    // nst = number of 4-edge steps; all guards wave-uniform. Loads issue
    // before FMAs (guarded blocks contain only the load) -> 4-deep MLP kept.
    auto gather = [&](int nst) {
        const float2* ep = &esw[wave][sub * 16];
#pragma unroll
        for (int b = 0; b < 4; b++) {
            int s0 = b * 4;
            if (s0 < nst) {
                f32x4 p01 = *(const f32x4*)(ep + s0);
                f32x4 p23 = *(const f32x4*)(ep + s0 + 2);
                bool g1 = s0 + 1 < nst, g2 = s0 + 2 < nst, g3 = s0 + 3 < nst;
                auto u0 = ld(__float_as_int(p01.x) + foff);
                decltype(u0) u1, u2, u3;
                if (g1) u1 = ld(__float_as_int(p01.z) + foff);
                if (g2) u2 = ld(__float_as_int(p23.x) + foff);
                if (g3) u3 = ld(__float_as_int(p23.z) + foff);
                fmaN(u0, p01.y);
                if (g1) fmaN(u1, p01.w);
                if (g2) fmaN(u2, p23.y);
                if (g3) fmaN(u3, p23.w);
            }
        }
    };

    if (deg <= 64) {
        int e = start + lane;
        int s = 0; float w = 0.f;
        if (e < end) { s = src_sorted[e]; w = __expf(lrelu(asrc[s] + ad)); }
        float dsum = wave_sum_bcast(w);
        esw[wave][tpos] = make_float2(__int_as_float(s << SH), w * (1.0f / dsum));
        gather((deg + 3) >> 2);
    } else {
        float part = 0.f;
        for (int cs = start; cs < end; cs += 64) {
            int e = cs + lane;
            if (e < end) part += __expf(lrelu(asrc[src_sorted[e]] + ad));
        }
        float inv = 1.0f / wave_sum_bcast(part);
        for (int cs = start; cs < end; cs += 64) {
            int e = cs + lane;
            int s = 0; float w = 0.f;
            if (e < end) { s = src_sorted[e]; w = __expf(lrelu(asrc[s] + ad)) * inv; }
            esw[wave][tpos] = make_float2(__int_as_float(s << SH), w);
            gather((min(64, end - cs) + 3) >> 2);
        }
    }

    // reduce the 4 edge-subsets, redistribute to per-lane final feats
    if constexpr (MODE == 2) {
        *reinterpret_cast<f32x4*>(&red[wave][sub][(lane & 15) * 4]) =
            (f32x4){acc[0], acc[1], acc[2], acc[3]};
        float t = 0.f;
#pragma unroll
        for (int g = 0; g < 4; g++) t += red[wave][g][lane];
        if (lane < 40) outf[(size_t)node * 40 + lane] = t + bias[lane];
    } else {
        f32x4* dst = reinterpret_cast<f32x4*>(&red[wave][sub][(lane & 15) * 8]);
        dst[0] = (f32x4){acc[0], acc[1], acc[2], acc[3]};
        dst[1] = (f32x4){acc[4], acc[5], acc[6], acc[7]};
        f32x2 tsum = (f32x2){0.f, 0.f};
#pragma unroll
        for (int g = 0; g < 4; g++)
            tsum += *reinterpret_cast<const f32x2*>(&red[wave][g][lane * 2]);

        if constexpr (MODE == 0) {
            // epilogue: bias+BN+tanh, fp8-pair write, fused next-layer alphas
            float vals[2];
#pragma unroll
            for (int v = 0; v < 2; v++) {
                int f = lane * 2 + v;
                float val = tsum[v] + bias[f];
                float rs = rsqrtf(rvar[f] + BN_EPS);
                vals[v] = tanh_fast((val - rmean[f]) * rs * gamma[f] + beta[f]);
            }
            ohi[(size_t)node * 64 + lane] = pk_fp8(vals[0], vals[1]);
            float ps = vals[0] * wsn[lane * 2] + vals[1] * wsn[lane * 2 + 1];
            float pd = vals[0] * wdn[lane * 2] + vals[1] * wdn[lane * 2 + 1];
            ps = wave_sum63(ps);
            pd = wave_sum63(pd);
            if (lane == 63) { asrc_n[node] = ps; adst_n[node] = pd; }
        } else {
            // fragment-major bf16-hi write (next GEMM's A)
            const size_t CSTRIDE = (size_t)N_NODES * 32;
            unsigned w0 = (unsigned)f2bf(tsum[0]) | ((unsigned)f2bf(tsum[1]) << 16);
            size_t a = (size_t)(lane >> 4) * CSTRIDE + (size_t)node * 32 + ((lane * 2) & 31);
            *reinterpret_cast<unsigned*>(ohi + a) = w0;
        }
    }
}

// ---------------------------------------------------------------------------

static inline size_t align256(size_t x) { return (x + 255) & ~(size_t)255; }

extern "C" void kernel_launch(void* const* d_in, const int* in_sizes, int n_in,
                              void* d_out, int out_size, void* d_ws, size_t ws_size,
                              hipStream_t stream) {
    const float* x   = (const float*)d_in[0];
    const int* ei    = (const int*)d_in[1];
    const float* w1  = (const float*)d_in[2];
    const float* as1 = (const float*)d_in[3];
    const float* ad1 = (const float*)d_in[4];
    const float* b1  = (const float*)d_in[5];
    const float* g1  = (const float*)d_in[6];
    const float* be1 = (const float*)d_in[7];
    const float* rm1 = (const float*)d_in[8];
    const float* rv1 = (const float*)d_in[9];
    const float* w2  = (const float*)d_in[10];
    const float* as2 = (const float*)d_in[11];
    const float* ad2 = (const float*)d_in[12];
    const float* b2  = (const float*)d_in[13];
    const float* g2  = (const float*)d_in[14];
    const float* be2 = (const float*)d_in[15];
    const float* rm2 = (const float*)d_in[16];
    const float* rv2 = (const float*)d_in[17];
    const float* w3  = (const float*)d_in[18];
    const float* as3 = (const float*)d_in[19];
    const float* ad3 = (const float*)d_in[20];
    const float* b3  = (const float*)d_in[21];
    float* out = (float*)d_out;

    const size_t P128 = align256((size_t)N_NODES * 128 * 2);
    const size_t P256 = align256((size_t)N_NODES * 256 * 2);

    char* p = (char*)d_ws;
    // regA: o1fp8 (front quarter, dead after agg2) -> h3 f16 (front, ldh=64)
    char* regA = p; p += P256;
    // regB: CSR scratch (pairs/bh/totals/starts) -> h1 f16 (front, row-major)
    //       -> g2hi (front, fragment; live through gemm23_fused)
    char* regB = p; p += P256;
    unsigned short* o1p  = (unsigned short*)regA;   // fp8 pairs: N*64 u16
    unsigned short* h3h  = (unsigned short*)regA;   // f16, N*64 u16 (o1p dead)
    unsigned short* h1h  = (unsigned short*)regB;   // f16, N x 128
    unsigned short* g2hi = (unsigned short*)regB;
    // CSR scratch aliases regB front (dead before GEMM1 writes h1h)
    int* pairs  = (int*)regB;                                        // E ints
    int* bhist  = (int*)(regB + align256((size_t)TOT_EDGES * 4));    // NBA*NBKT
    int* totals = (int*)((char*)bhist + align256((size_t)NBA * NBKT * 4));
    int* starts = (int*)((char*)totals + align256((size_t)NBKT * 4)); // NBKT+1

    float* asrcA = (float*)p; p += align256((size_t)N_NODES * 4);
    float* adstA = (float*)p; p += align256((size_t)N_NODES * 4);
    float* asrcB = (float*)p; p += align256((size_t)N_NODES * 4);
    float* adstB = (float*)p; p += align256((size_t)N_NODES * 4);
    int* row_ptr   = (int*)p; p += align256((size_t)(N_NODES + 1) * 4);
    int* src_sorted = (int*)p; p += align256((size_t)TOT_EDGES * 4);
    unsigned short* w1th = (unsigned short*)p; p += align256(128 * 128 * 2);
    unsigned short* w1tl = (unsigned short*)p; p += align256(128 * 128 * 2);
    unsigned short* w2th = (unsigned short*)p; p += align256(256 * 128 * 2);
    unsigned short* w2tl = (unsigned short*)p; p += align256(256 * 128 * 2);
    unsigned short* w3th = (unsigned short*)p; p += align256(48 * 256 * 2);
    unsigned short* w3tl = (unsigned short*)p; p += align256(48 * 256 * 2);
    unsigned short* ab1h = (unsigned short*)p; p += align256(16 * 128 * 2);
    unsigned short* ab1l = (unsigned short*)p; p += align256(16 * 128 * 2);
    unsigned short* ab3h = (unsigned short*)p; p += align256(16 * 256 * 2);
    unsigned short* ab3l = (unsigned short*)p; p += align256(16 * 256 * 2);
    float* ws2f = (float*)p; p += align256(128 * 4);
    float* wd2f = (float*)p; p += align256(128 * 4);
    float* bn2S = (float*)p; p += align256(256 * 4);
    float* bn2T = (float*)p; p += align256(256 * 4);

    const int WTOT = 128 * 128 + 256 * 128 + 48 * 256 + 2048 + 4096 + 256 + 256;

    wprep_all<<<(WTOT + 255) / 256, 256, 0, stream>>>(
        w1, w2, w3, as1, ad1, as2, ad2, as3, ad3,
        b2, g2, be2, rm2, rv2,
        w1th, w1tl, w2th, w2tl, w3th, w3tl,
        ab1h, ab1l, ab3h, ab3l, ws2f, wd2f, bn2S, bn2T);

    // CSR build: two-level LDS counting sort (no global atomics)
    csr_hist<<<NBA, 256, 0, stream>>>(ei, bhist);
    csr_scan_blocks<<<NBKT, 512, 0, stream>>>(bhist, totals);
    csr_scan_buckets<<<1, 512, 0, stream>>>(totals, starts);
    csr_scatter<<<NBA, 256, 0, stream>>>(ei, bhist, starts, pairs);
    csr_build<<<NBKT, 256, 0, stream>>>(pairs, starts, row_ptr, src_sorted);

    const int NWB = (N_NODES + 3) / 4;
    const int G64 = (N_NODES + 63) / 64;
    const int G32 = (N_NODES + 31) / 32;

    // --- Layer 1: h1 = x@w1 (+alpha1), A = x f32 DIRECT (inline split),
    //     C row-major f16; agg1(wide) -> o1 (fp8) ---
    mfma_gemm<128, 2, 1, 4, 128, true, true, false, false, true, true><<<G64, 256, 0, stream>>>(
        (const unsigned short*)x, nullptr, w1th, w1tl, ab1h, ab1l, h1h, 128,
        nullptr, nullptr, nullptr, nullptr, nullptr, asrcA, adstA, N_NODES);
    gat_agg_wide<0><<<NWB, 256, 0, stream>>>(
        h1h, asrcA, adstA, row_ptr, src_sorted,
        b1, g1, be1, rm1, rv1, ws2f, wd2f,
        o1p, nullptr, asrcB, adstB);

    // --- Layer 2 (commuted): g2 = S2(o1 fp8) -> fragment-major bf16-hi ---
    gat_agg_wide<1><<<NWB, 256, 0, stream>>>(
        o1p, asrcB, adstB, row_ptr, src_sorted,
        nullptr, nullptr, nullptr, nullptr, nullptr, nullptr, nullptr,
        g2hi, nullptr, nullptr, nullptr);

    // --- Layers 2+3 fused (32-row v4): o2 = tanh(g2@w2*S+T) -> LDS ->
    //     h3 = o2@w3 (+alpha3); h3 overwrites o1p region (dead) ---
    gemm23_fused<<<G32, 256, 0, stream>>>(
        g2hi, w2th, w2tl, bn2S, bn2T,
        w3th, w3tl, ab3h, ab3l, h3h, asrcA, adstA, N_NODES);

    // --- Layer 3 aggregation -> out ---
    gat_agg_wide<2><<<NWB, 256, 0, stream>>>(
        h3h, asrcA, adstA, row_ptr, src_sorted,
        b3, nullptr, nullptr, nullptr, nullptr, nullptr, nullptr,
        nullptr, out, nullptr, nullptr);
}

// Round 11
// 436.612 us; speedup vs baseline: 1.0176x; 1.0176x over previous
//
#include <hip/hip_runtime.h>
#include <hip/hip_bf16.h>
#include <cstddef>

#define N_NODES 100000
#define E_EDGES 1600000
#define TOT_EDGES (E_EDGES + N_NODES)
#define NEG_SLOPE 0.2f
#define BN_EPS 1e-5f
#define NBKT ((N_NODES + 255) / 256)   /* 391 coarse buckets (dst>>8) */
#define NBA 512                        /* blocks in CSR pass A */

typedef __attribute__((ext_vector_type(8))) short short8;
typedef __attribute__((ext_vector_type(4))) float f32x4;
typedef __attribute__((ext_vector_type(2))) float f32x2;
typedef __attribute__((ext_vector_type(4))) int int32x4;
typedef __attribute__((ext_vector_type(2))) int int32x2;
typedef _Float16 h16x2 __attribute__((ext_vector_type(2)));

#if defined(__has_builtin)
#if __has_builtin(__builtin_amdgcn_make_buffer_rsrc) && __has_builtin(__builtin_amdgcn_raw_buffer_load_b128)
#define HAVE_BUFRSRC 1
#endif
#if __has_builtin(__builtin_amdgcn_make_buffer_rsrc) && __has_builtin(__builtin_amdgcn_raw_buffer_load_b64)
#define HAVE_BUF64 1
#endif
#endif

__device__ __forceinline__ unsigned short f2bf(float f) {
    union { float f; unsigned u; } c; c.f = f;
    unsigned u = c.u;
    u += 0x7fffu + ((u >> 16) & 1u);
    return (unsigned short)(u >> 16);
}
__device__ __forceinline__ float bf2f(unsigned short h) {
    union { unsigned u; float f; } c; c.u = ((unsigned)h) << 16;
    return c.f;
}
// f16 helpers (h1/h3 gather payloads are f16: better mantissa than bf16 in
// this range AND (float)h * w + acc fuses to v_fma_mix_f32)
__device__ __forceinline__ unsigned short f2h(float f) {
    union { _Float16 h; unsigned short u; } c; c.h = (_Float16)f; return c.u;
}
__device__ __forceinline__ float lrelu(float t) {
    return (t > 0.f) ? t : NEG_SLOPE * t;
}
// fast tanh: 1 - 2/(e^{2x}+1). |err| ~1e-6 absolute; saturates correctly.
__device__ __forceinline__ float tanh_fast(float x) {
    float e = __expf(2.f * x);
    return 1.f - 2.f / (e + 1.f);
}
// HW fp8 (e4m3 on gfx950) pack/unpack via inline asm — self-consistent
// roundtrip (encode and decode use the same HW interpretation).
__device__ __forceinline__ unsigned short pk_fp8(float a, float b) {
    unsigned v;
    asm volatile("v_cvt_pk_fp8_f32 %0, %1, %2" : "=v"(v) : "v"(a), "v"(b));
    return (unsigned short)v;
}
__device__ __forceinline__ f32x2 unpk_fp8(unsigned u) {
    f32x2 r;
    asm volatile("v_cvt_pk_f32_fp8 %0, %1" : "=v"(r) : "v"(u));
    return r;
}

// ---------------------------------------------------------------------------
// DPP wave-64 sum (VALU pipe, ~6 dependent adds). Result valid in LANE 63.
// bound_ctrl=true: invalid source lanes contribute 0 (correct for add).
// ---------------------------------------------------------------------------
__device__ __forceinline__ float wave_sum63(float x) {
    x += __int_as_float(__builtin_amdgcn_update_dpp(0, __float_as_int(x), 0x111, 0xf, 0xf, true)); // row_shr:1
    x += __int_as_float(__builtin_amdgcn_update_dpp(0, __float_as_int(x), 0x112, 0xf, 0xf, true)); // row_shr:2
    x += __int_as_float(__builtin_amdgcn_update_dpp(0, __float_as_int(x), 0x114, 0xf, 0xf, true)); // row_shr:4
    x += __int_as_float(__builtin_amdgcn_update_dpp(0, __float_as_int(x), 0x118, 0xf, 0xf, true)); // row_shr:8
    x += __int_as_float(__builtin_amdgcn_update_dpp(0, __float_as_int(x), 0x142, 0xf, 0xf, true)); // row_bcast:15
    x += __int_as_float(__builtin_amdgcn_update_dpp(0, __float_as_int(x), 0x143, 0xf, 0xf, true)); // row_bcast:31
    return x;
}
__device__ __forceinline__ float wave_sum_bcast(float x) {
    return __int_as_float(__builtin_amdgcn_readlane(__float_as_int(wave_sum63(x)), 63));
}

// ---------------------------------------------------------------------------
// CSR build — two-level LDS counting sort, ZERO global atomics.
// ---------------------------------------------------------------------------

__global__ __launch_bounds__(256) void csr_hist(const int* __restrict__ ei,
                                                int* __restrict__ bh) {
    __shared__ int h[NBKT];
    int t = threadIdx.x;
    for (int b = t; b < NBKT; b += 256) h[b] = 0;
    __syncthreads();
    int idx = blockIdx.x * 256 + t;
    const int stride = NBA * 256;
    for (int e = idx; e < TOT_EDGES; e += stride) {
        int d = (e < E_EDGES) ? ei[E_EDGES + e] : (e - E_EDGES);
        atomicAdd(&h[((unsigned)d) >> 8], 1);
    }
    __syncthreads();
    for (int b = t; b < NBKT; b += 256) bh[blockIdx.x * NBKT + b] = h[b];
}

// per-bin exclusive scan over the NBA block histograms (one block per bin)
__global__ __launch_bounds__(512) void csr_scan_blocks(int* __restrict__ bh,
                                                       int* __restrict__ totals) {
    __shared__ int s[NBA];
    int t = threadIdx.x, bin = blockIdx.x;
    int v = bh[t * NBKT + bin];
    s[t] = v;
    __syncthreads();
    for (int off = 1; off < NBA; off <<= 1) {
        int y = (t >= off) ? s[t - off] : 0;
        __syncthreads();
        s[t] += y;
        __syncthreads();
    }
    bh[t * NBKT + bin] = s[t] - v;          // exclusive offset for block t
    if (t == NBA - 1) totals[bin] = s[t];   // bucket total
}

// exclusive scan over bucket totals -> bucket start positions
__global__ __launch_bounds__(512) void csr_scan_buckets(const int* __restrict__ totals,
                                                        int* __restrict__ starts) {
    __shared__ int s[512];
    int t = threadIdx.x;
    int v = (t < NBKT) ? totals[t] : 0;
    s[t] = v;
    __syncthreads();
    for (int off = 1; off < 512; off <<= 1) {
        int y = (t >= off) ? s[t - off] : 0;
        __syncthreads();
        s[t] += y;
        __syncthreads();
    }
    if (t < NBKT) starts[t] = s[t] - v;
    if (t == 0) starts[NBKT] = TOT_EDGES;
}

__global__ __launch_bounds__(256) void csr_scatter(const int* __restrict__ ei,
                                                   const int* __restrict__ bh,
                                                   const int* __restrict__ starts,
                                                   int* __restrict__ pairs) {
    __shared__ int wp[NBKT];
    int t = threadIdx.x;
    for (int b = t; b < NBKT; b += 256)
        wp[b] = starts[b] + bh[blockIdx.x * NBKT + b];
    __syncthreads();
    int idx = blockIdx.x * 256 + t;
    const int stride = NBA * 256;
    for (int e = idx; e < TOT_EDGES; e += stride) {
        int s, d;
        if (e < E_EDGES) { s = ei[e]; d = ei[E_EDGES + e]; }
        else             { s = e - E_EDGES; d = s; }
        int pos = atomicAdd(&wp[((unsigned)d) >> 8], 1);
        pairs[pos] = s | ((d & 255) << 20);
    }
}

__global__ __launch_bounds__(256) void csr_build(const int* __restrict__ pairs,
                                                 const int* __restrict__ starts,
                                                 int* __restrict__ row_ptr,
                                                 int* __restrict__ src_sorted) {
    __shared__ int nh[256];
    __shared__ int sc[256];
    __shared__ int wp[256];
    int k = blockIdx.x, t = threadIdx.x;
    int bs = starts[k], be = starts[k + 1];
    nh[t] = 0;
    __syncthreads();
    for (int i = bs + t; i < be; i += 256)
        atomicAdd(&nh[((unsigned)pairs[i]) >> 20], 1);
    __syncthreads();
    int v = nh[t];
    sc[t] = v;
    __syncthreads();
    for (int off = 1; off < 256; off <<= 1) {
        int y = (t >= off) ? sc[t - off] : 0;
        __syncthreads();
        sc[t] += y;
        __syncthreads();
    }
    int excl = sc[t] - v;
    int node = k * 256 + t;
    if (node <= N_NODES) row_ptr[node] = bs + excl;  // row_ptr[N] from last bucket
    wp[t] = bs + excl;
    __syncthreads();
    for (int i = bs + t; i < be; i += 256) {
        unsigned p = (unsigned)pairs[i];
        int pos = atomicAdd(&wp[p >> 20], 1);
        src_sorted[pos] = (int)(p & 0xFFFFFu);
    }
}

// weight transposes + alpha vectors + folded BN2 (S,T), one launch
__global__ __launch_bounds__(256) void wprep_all(
    const float* __restrict__ w1, const float* __restrict__ w2, const float* __restrict__ w3,
    const float* __restrict__ as1, const float* __restrict__ ad1,
    const float* __restrict__ as2, const float* __restrict__ ad2,
    const float* __restrict__ as3, const float* __restrict__ ad3,
    const float* __restrict__ b2a, const float* __restrict__ g2a,
    const float* __restrict__ be2a, const float* __restrict__ rm2a,
    const float* __restrict__ rv2a,
    unsigned short* __restrict__ w1th, unsigned short* __restrict__ w1tl,
    unsigned short* __restrict__ w2th, unsigned short* __restrict__ w2tl,
    unsigned short* __restrict__ w3th, unsigned short* __restrict__ w3tl,
    unsigned short* __restrict__ ab1h, unsigned short* __restrict__ ab1l,
    unsigned short* __restrict__ ab3h, unsigned short* __restrict__ ab3l,
    float* __restrict__ ws2f, float* __restrict__ wd2f,
    float* __restrict__ bn2S, float* __restrict__ bn2T) {
    const int T1 = 128 * 128, T2 = 256 * 128, T3 = 48 * 256;
    const int W = T1 + T2 + T3;
    int idx = blockIdx.x * 256 + threadIdx.x;
    if (idx < W) {
        float v; unsigned short* th; unsigned short* tl; int o;
        if (idx < T1) {
            int n = idx / 128, k = idx % 128;
            v = w1[k * 128 + n]; th = w1th; tl = w1tl; o = idx;
        } else if (idx < T1 + T2) {
            int i = idx - T1; int n = i / 128, k = i % 128;
            v = w2[k * 256 + n]; th = w2th; tl = w2tl; o = i;
        } else {
            int i = idx - T1 - T2; int n = i / 256, k = i % 256;
            v = (n < 40) ? w3[k * 40 + n] : 0.f; th = w3th; tl = w3tl; o = i;
        }
        unsigned short h = f2bf(v);
        th[o] = h;
        tl[o] = f2bf(v - bf2f(h));
        return;
    }
    int j = idx - W;
    if (j < 2048) {
        int r = j / 128, k = j % 128;
        float v = 0.f;
        if (r < 2) {
            const float* a = r ? ad1 : as1;
            const float* wr = w1 + (size_t)k * 128;
            for (int n = 0; n < 128; n++) v += wr[n] * a[n];
        }
        unsigned short h = f2bf(v);
        ab1h[j] = h; ab1l[j] = f2bf(v - bf2f(h));
    } else if (j < 2048 + 4096) {
        int i = j - 2048; int r = i / 256, k = i % 256;
        float v = 0.f;
        if (r < 2) {
            const float* a = r ? ad3 : as3;
            const float* wr = w3 + (size_t)k * 40;
            for (int n = 0; n < 40; n++) v += wr[n] * a[n];
        }
        unsigned short h = f2bf(v);
        ab3h[i] = h; ab3l[i] = f2bf(v - bf2f(h));
    } else if (j < 2048 + 4096 + 256) {
        int i = j - 2048 - 4096; int r = i / 128, k = i % 128;
        const float* a = r ? ad2 : as2;
        const float* wr = w2 + (size_t)k * 256;
        float v = 0.f;
        for (int n = 0; n < 256; n++) v += wr[n] * a[n];
        if (r == 0) ws2f[k] = v; else wd2f[k] = v;
    } else if (j < 2048 + 4096 + 256 + 256) {
        int i = j - 2048 - 4096 - 256;   // col 0..255
        float S = rsqrtf(rv2a[i] + BN_EPS) * g2a[i];
        bn2S[i] = S;
        bn2T[i] = (b2a[i] - rm2a[i]) * S + be2a[i];
    }
}

// ---------------------------------------------------------------------------
// Split-bf16 MFMA GEMM (used for layer-1 only now).
// AF32:  A read directly from row-major f32 (stride K), split hi/lo INLINE.
// ---------------------------------------------------------------------------
template<int K, int NTILES, int MWAVES, int NWAVES, int NACT, bool ASPLIT, bool ALPHA, bool BNT, bool CFRAG, bool CHALF, bool AF32>
__global__ __launch_bounds__(256) void mfma_gemm(
    const unsigned short* __restrict__ Ahi, const unsigned short* __restrict__ Alo,
    const unsigned short* __restrict__ BThi, const unsigned short* __restrict__ BTlo,
    const unsigned short* __restrict__ ABh, const unsigned short* __restrict__ ABl,
    unsigned short* __restrict__ Chi, int ldc,
    const float* __restrict__ bias, const float* __restrict__ gamma,
    const float* __restrict__ beta, const float* __restrict__ rmean,
    const float* __restrict__ rvar,
    float* __restrict__ asrc, float* __restrict__ adst, int M)
{
    int lane = threadIdx.x & 63;
    int wave = threadIdx.x >> 6;
    int quad = lane >> 4;
    int l16  = lane & 15;
    long mbase = (long)blockIdx.x * (64 * MWAVES) + (long)(wave / NWAVES) * 64;
    int n0 = ((wave % NWAVES) + blockIdx.y * NWAVES) * (NTILES * 16);
    bool aw = ((wave % NWAVES) == 0) && (blockIdx.y == 0);
    const size_t CSTRIDE = (size_t)M * 32;  // fragment chunk stride (u16)

    size_t roff[4];
#pragma unroll
    for (int i = 0; i < 4; i++) {
        long r = mbase + i * 16 + l16;
        if (r > M - 1) r = M - 1;
        roff[i] = AF32 ? ((size_t)r * K + (size_t)(quad * 8))    // f32 units
                       : ((size_t)r * 32 + (size_t)(quad * 8));  // u16 units
    }
    const unsigned short* bh[NTILES]; const unsigned short* bl[NTILES];
#pragma unroll
    for (int j = 0; j < NTILES; j++) {
        long n = n0 + j * 16 + l16;
        bh[j] = BThi + n * K; bl[j] = BTlo + n * K;
    }
    const unsigned short* bah = nullptr; const unsigned short* bal = nullptr;
    if constexpr (ALPHA) { bah = ABh + (size_t)l16 * K; bal = ABl + (size_t)l16 * K; }
    const int ko = quad * 8;

    f32x4 acc[4][NTILES];
    f32x4 acca[4];
#pragma unroll
    for (int i = 0; i < 4; i++) {
        acca[i] = (f32x4){0.f, 0.f, 0.f, 0.f};
#pragma unroll
        for (int j = 0; j < NTILES; j++)
            acc[i][j] = (f32x4){0.f, 0.f, 0.f, 0.f};
    }

    for (int kc = 0; kc < K / 32; kc++) {
        const int k0 = kc * 32;
        short8 vah[4], vall[4], vbh[NTILES], vbl[NTILES];
#pragma unroll
        for (int i = 0; i < 4; i++) {
            if constexpr (AF32) {
                const float* xf = (const float*)Ahi;
                const float* pa = xf + roff[i] + kc * 32;
                f32x4 va = *(const f32x4*)pa;
                f32x4 vb = *(const f32x4*)(pa + 4);
#pragma unroll
                for (int q = 0; q < 8; q++) {
                    float v = (q < 4) ? va[q] : vb[q - 4];
                    unsigned short h = f2bf(v);
                    vah[i][q] = (short)h;
                    vall[i][q] = (short)f2bf(v - bf2f(h));
                }
            } else {
                const unsigned short* Ah = Ahi + (size_t)kc * CSTRIDE;
                vah[i] = *(const short8*)(Ah + roff[i]);
                if constexpr (ASPLIT) {
                    const unsigned short* Al = Alo + (size_t)kc * CSTRIDE;
                    vall[i] = *(const short8*)(Al + roff[i]);
                }
            }
        }
#pragma unroll
        for (int j = 0; j < NTILES; j++) {
            vbh[j] = *(const short8*)(bh[j] + k0 + ko);
            vbl[j] = *(const short8*)(bl[j] + k0 + ko);
        }
#pragma unroll
        for (int i = 0; i < 4; i++)
#pragma unroll
            for (int j = 0; j < NTILES; j++) {
                acc[i][j] = __builtin_amdgcn_mfma_f32_16x16x32_bf16(vah[i], vbh[j], acc[i][j], 0, 0, 0);
                acc[i][j] = __builtin_amdgcn_mfma_f32_16x16x32_bf16(vah[i], vbl[j], acc[i][j], 0, 0, 0);
                if constexpr (ASPLIT)
                    acc[i][j] = __builtin_amdgcn_mfma_f32_16x16x32_bf16(vall[i], vbh[j], acc[i][j], 0, 0, 0);
            }
        if constexpr (ALPHA) {
            if (aw) {
                short8 vbah = *(const short8*)(bah + k0 + ko);
                short8 vbal = *(const short8*)(bal + k0 + ko);
#pragma unroll
                for (int i = 0; i < 4; i++) {
                    acca[i] = __builtin_amdgcn_mfma_f32_16x16x32_bf16(vah[i], vbah, acca[i], 0, 0, 0);
                    acca[i] = __builtin_amdgcn_mfma_f32_16x16x32_bf16(vah[i], vbal, acca[i], 0, 0, 0);
                    if constexpr (ASPLIT)
                        acca[i] = __builtin_amdgcn_mfma_f32_16x16x32_bf16(vall[i], vbah, acca[i], 0, 0, 0);
                }
            }
        }
    }

#pragma unroll
    for (int i = 0; i < 4; i++)
#pragma unroll
        for (int j = 0; j < NTILES; j++) {
            int col = n0 + j * 16 + l16;
            float bb = 0.f, rs = 1.f, gg = 1.f, bt = 0.f, rm = 0.f;
            if constexpr (BNT) {
                bb = bias[col]; gg = gamma[col]; bt = beta[col];
                rm = rmean[col]; rs = rsqrtf(rvar[col] + BN_EPS);
            }
#pragma unroll
            for (int r = 0; r < 4; r++) {
                long row = mbase + i * 16 + quad * 4 + r;
                if (row < M && col < NACT) {
                    float v = acc[i][j][r];
                    if constexpr (BNT) v = tanh_fast((v + bb - rm) * rs * gg + bt);
                    if constexpr (CFRAG) {
                        Chi[(size_t)(col >> 5) * CSTRIDE + (size_t)row * 32 + (col & 31)] = f2bf(v);
                    } else {
                        Chi[row * ldc + col] = CHALF ? f2h(v) : f2bf(v);
                    }
                }
            }
        }
    if constexpr (ALPHA) {
        if (aw) {
#pragma unroll
            for (int i = 0; i < 4; i++)
#pragma unroll
                for (int r = 0; r < 4; r++) {
                    long row = mbase + i * 16 + quad * 4 + r;
                    if (row < M) {
                        float v = acca[i][r];
                        if (l16 == 0) asrc[row] = v;
                        else if (l16 == 1) adst[row] = v;
                    }
                }
        }
    }
}

// ---------------------------------------------------------------------------
// gemm23_fused (v3 config — best measured at 78.0 µs): 512 threads / 8 waves
// per 64-row block, 40 KB LDS. Round-10 lesson: 32-row tile (v4) regressed
// (occupancy FELL to 28%, +VGPR, 2x B-panel traffic) — the stall is the
// block's internal load pipeline, not residency caps. Reverting to best
// measured structure; XCD swizzle dropped (proven no-op: L2 is flushed
// between dispatches, so cross-kernel producer/consumer L2 reuse can't work).
//   phase 1: wave w -> cols w*32..+31 (acc[4][2]); kc fully unrolled.
//   phase 2: 8 wave-tasks {row half} x {3 col-tiles + alpha}; kc-parity
//            split accumulators (4 chains x 8-deep).
// ---------------------------------------------------------------------------
__global__ __launch_bounds__(512) void gemm23_fused(
    const unsigned short* __restrict__ Ahi,   // g2hi fragment-major, K=128
    const unsigned short* __restrict__ B2h, const unsigned short* __restrict__ B2l,
    const float* __restrict__ bnS, const float* __restrict__ bnT,
    const unsigned short* __restrict__ B3h, const unsigned short* __restrict__ B3l,
    const unsigned short* __restrict__ AB3h, const unsigned short* __restrict__ AB3l,
    unsigned short* __restrict__ h3,          // f16, ldh=64, cols 0..47
    float* __restrict__ asrc, float* __restrict__ adst, int M)
{
    constexpr int LW = 40;                    // LDS row stride in u16
    __shared__ unsigned short o2l[8 * 64 * LW];   // 40 KB

    int lane = threadIdx.x & 63;
    int wave = threadIdx.x >> 6;              // 0..7
    int quad = lane >> 4;
    int l16  = lane & 15;
    long mbase = (long)blockIdx.x * 64;
    const size_t CSTRIDE = (size_t)M * 32;
    const int ko = quad * 8;

    // ---- phase 1: GEMM2 tile (64 x 256); wave w -> cols w*32..+31 ----
    size_t roff[4];
#pragma unroll
    for (int i = 0; i < 4; i++) {
        long r = mbase + i * 16 + l16;
        if (r > M - 1) r = M - 1;
        roff[i] = (size_t)r * 32 + (size_t)ko;
    }
    int n0 = wave * 32;
    const unsigned short* bh[2]; const unsigned short* bl[2];
#pragma unroll
    for (int j = 0; j < 2; j++) {
        long n = n0 + j * 16 + l16;
        bh[j] = B2h + n * 128; bl[j] = B2l + n * 128;
    }

    f32x4 acc[4][2];
#pragma unroll
    for (int i = 0; i < 4; i++)
#pragma unroll
        for (int j = 0; j < 2; j++)
            acc[i][j] = (f32x4){0.f, 0.f, 0.f, 0.f};

#pragma unroll
    for (int kc = 0; kc < 4; kc++) {
        const int k0 = kc * 32;
        const unsigned short* Ah = Ahi + (size_t)kc * CSTRIDE;
        short8 vah[4], vbh[2], vbl[2];
#pragma unroll
        for (int i = 0; i < 4; i++) vah[i] = *(const short8*)(Ah + roff[i]);
#pragma unroll
        for (int j = 0; j < 2; j++) {
            vbh[j] = *(const short8*)(bh[j] + k0 + ko);
            vbl[j] = *(const short8*)(bl[j] + k0 + ko);
        }
#pragma unroll
        for (int i = 0; i < 4; i++)
#pragma unroll
            for (int j = 0; j < 2; j++) {
                acc[i][j] = __builtin_amdgcn_mfma_f32_16x16x32_bf16(vah[i], vbh[j], acc[i][j], 0, 0, 0);
                acc[i][j] = __builtin_amdgcn_mfma_f32_16x16x32_bf16(vah[i], vbl[j], acc[i][j], 0, 0, 0);
            }
    }

    // folded-BN + tanh epilogue -> LDS (bf16, fragment layout, stride LW)
#pragma unroll
    for (int j = 0; j < 2; j++) {
        int col = n0 + j * 16 + l16;
        float S = bnS[col], T = bnT[col];
        int cbase = (col >> 5) * 64 * LW + (col & 31);
#pragma unroll
        for (int i = 0; i < 4; i++)
#pragma unroll
            for (int r = 0; r < 4; r++) {
                int li = i * 16 + quad * 4 + r;
                o2l[cbase + li * LW] = f2bf(tanh_fast(acc[i][j][r] * S + T));
            }
    }
    __syncthreads();

    // ---- phase 2: 8 wave-tasks = {row half} x {3 col-tiles + alpha} ----
    int rh   = wave >> 2;             // rows rh*32 .. +31
    int task = wave & 3;              // 0..2 = col tile, 3 = alpha
    int lrow0 = rh * 32 + l16;        // row-fragment i=0
    int lrow1 = rh * 32 + 16 + l16;   // row-fragment i=1

    const unsigned short* p3h;
    const unsigned short* p3l;
    if (task < 3) {
        p3h = B3h + (size_t)(task * 16 + l16) * 256;
        p3l = B3l + (size_t)(task * 16 + l16) * 256;
    } else {
        p3h = AB3h + (size_t)l16 * 256;
        p3l = AB3l + (size_t)l16 * 256;
    }

    // kc-parity split: 4 chains x 8-deep
    f32x4 a3[2][2];
#pragma unroll
    for (int i = 0; i < 2; i++)
#pragma unroll
        for (int pp = 0; pp < 2; pp++)
            a3[i][pp] = (f32x4){0.f, 0.f, 0.f, 0.f};

#pragma unroll
    for (int kc = 0; kc < 8; kc++) {
        const int k0 = kc * 32;
        const int par = kc & 1;
        short8 a0 = *(const short8*)(o2l + (kc * 64 + lrow0) * LW + ko);
        short8 a1 = *(const short8*)(o2l + (kc * 64 + lrow1) * LW + ko);
        short8 vh = *(const short8*)(p3h + k0 + ko);
        short8 vl = *(const short8*)(p3l + k0 + ko);
        a3[0][par] = __builtin_amdgcn_mfma_f32_16x16x32_bf16(a0, vh, a3[0][par], 0, 0, 0);
        a3[0][par] = __builtin_amdgcn_mfma_f32_16x16x32_bf16(a0, vl, a3[0][par], 0, 0, 0);
        a3[1][par] = __builtin_amdgcn_mfma_f32_16x16x32_bf16(a1, vh, a3[1][par], 0, 0, 0);
        a3[1][par] = __builtin_amdgcn_mfma_f32_16x16x32_bf16(a1, vl, a3[1][par], 0, 0, 0);
    }
    f32x4 r3[2];
    r3[0] = a3[0][0] + a3[0][1];
    r3[1] = a3[1][0] + a3[1][1];

    if (task < 3) {
        int col = task * 16 + l16;
#pragma unroll
        for (int i = 0; i < 2; i++)
#pragma unroll
            for (int r = 0; r < 4; r++) {
                long row = mbase + rh * 32 + i * 16 + quad * 4 + r;
                if (row < M) h3[(size_t)row * 64 + col] = f2h(r3[i][r]);
            }
    } else {
#pragma unroll
        for (int i = 0; i < 2; i++)
#pragma unroll
            for (int r = 0; r < 4; r++) {
                long row = mbase + rh * 32 + i * 16 + quad * 4 + r;
                if (row < M) {
                    if (l16 == 0) asrc[row] = r3[i][r];
                    else if (l16 == 1) adst[row] = r3[i][r];
                }
            }
    }
}

// ---------------------------------------------------------------------------
// gat_agg_wide<MODE>: fused segment-softmax + wide gather-aggregate.
// MODE 0 now accumulates in PACKED f16 (v_pk_fma_f16: 4 instr per 16B load
// instead of 8 v_fma_mix) — f16 accum noise (~2e-3 rel over deg~17) is ~15x
// below the fp8 quantization o1 already passes through. MODE 1/2 keep f32.
// ---------------------------------------------------------------------------
template<int MODE>
__global__ __launch_bounds__(256) void gat_agg_wide(
    const unsigned short* __restrict__ hsrc,
    const float* __restrict__ asrc, const float* __restrict__ adst,
    const int* __restrict__ row_ptr, const int* __restrict__ src_sorted,
    const float* __restrict__ bias, const float* __restrict__ gamma,
    const float* __restrict__ beta, const float* __restrict__ rmean,
    const float* __restrict__ rvar,
    const float* __restrict__ wsn, const float* __restrict__ wdn,
    unsigned short* __restrict__ ohi,
    float* __restrict__ outf,
    float* __restrict__ asrc_n, float* __restrict__ adst_n)
{
    constexpr int SH  = (MODE == 0) ? 8 : 7;     // log2(row bytes)
    constexpr int BPL = (MODE == 0) ? 16 : 8;    // bytes per lane
    constexpr int NF  = (MODE == 2) ? 4 : 8;     // feats accumulated per lane

    __shared__ __align__(16) float2 esw[4][64];      // transposed (src<<SH, w)
    __shared__ __align__(16) float red[4][4][132];   // [wave][sub][feat]

    int wave = threadIdx.x >> 6;
    int lane = threadIdx.x & 63;
    int node = blockIdx.x * 4 + wave;
    if (node >= N_NODES) return;

    int start = row_ptr[node];
    int end = row_ptr[node + 1];
    int deg = end - start;
    float ad = adst[node];
    int sub = lane >> 4;                       // which of 4 concurrent edges
    int foff = (lane & 15) * BPL;              // byte offset within row
    int tpos = (lane & 3) * 16 + (lane >> 2);  // transposed slot for lane's edge

#if defined(HAVE_BUFRSRC) && defined(HAVE_BUF64)
    auto rsrc = __builtin_amdgcn_make_buffer_rsrc((void*)hsrc, (short)0,
                                                  N_NODES << SH, 0x00020000);
#endif

    float acc[NF];
#pragma unroll
    for (int i = 0; i < NF; i++) acc[i] = 0.f;
    h16x2 acch[4];
#pragma unroll
    for (int i = 0; i < 4; i++) acch[i] = (h16x2){(_Float16)0.f, (_Float16)0.f};

    auto ld = [&](int vo) {
        if constexpr (MODE == 0) {
#if defined(HAVE_BUFRSRC) && defined(HAVE_BUF64)
            return __builtin_amdgcn_raw_buffer_load_b128(rsrc, vo, 0, 0);
#else
            return *reinterpret_cast<const int32x4*>(
                reinterpret_cast<const char*>(hsrc) + (unsigned)vo);
#endif
        } else {
#if defined(HAVE_BUFRSRC) && defined(HAVE_BUF64)
            return __builtin_amdgcn_raw_buffer_load_b64(rsrc, vo, 0, 0);
#else
            return *reinterpret_cast<const int32x2*>(
                reinterpret_cast<const char*>(hsrc) + (unsigned)vo);
#endif
        }
    };
    auto fmaN = [&](auto u, float ww) {
        if constexpr (MODE == 0) {
            // packed f16 accumulation: 4 v_pk_fma_f16 per 16B load
            union { decltype(u) v; h16x2 h[4]; } c; c.v = u;
            _Float16 wh = (_Float16)ww;
            h16x2 w2; w2[0] = wh; w2[1] = wh;
#pragma unroll
            for (int i = 0; i < 4; i++)
                acch[i] = c.h[i] * w2 + acch[i];
        } else if constexpr (MODE == 1) {
            union { decltype(u) v; unsigned w[2]; } c; c.v = u;
#pragma unroll
            for (int i = 0; i < 2; i++) {
                f32x2 lo = unpk_fp8(c.w[i]);
                f32x2 hi = unpk_fp8(c.w[i] >> 16);
                acc[4 * i]     += ww * lo.x;
                acc[4 * i + 1] += ww * lo.y;
                acc[4 * i + 2] += ww * hi.x;
                acc[4 * i + 3] += ww * hi.y;
            }
        } else {
            union { decltype(u) v; unsigned w[2]; } c; c.v = u;
#pragma unroll
            for (int i = 0; i < 2; i++) {
                union { unsigned u; _Float16 h[2]; } t; t.u = c.w[i];
                acc[2 * i]     += ww * (float)t.h[0];   // v_fma_mix_f32
                acc[2 * i + 1] += ww * (float)t.h[1];
            }
        }
    };
    // nst = number of 4-edge steps; all guards wave-uniform. Loads issue
    // before FMAs (guarded blocks contain only the load) -> 4-deep MLP kept.
    auto gather = [&](int nst) {
        const float2* ep = &esw[wave][sub * 16];
#pragma unroll
        for (int b = 0; b < 4; b++) {
            int s0 = b * 4;
            if (s0 < nst) {
                f32x4 p01 = *(const f32x4*)(ep + s0);
                f32x4 p23 = *(const f32x4*)(ep + s0 + 2);
                bool g1 = s0 + 1 < nst, g2 = s0 + 2 < nst, g3 = s0 + 3 < nst;
                auto u0 = ld(__float_as_int(p01.x) + foff);
                decltype(u0) u1, u2, u3;
                if (g1) u1 = ld(__float_as_int(p01.z) + foff);
                if (g2) u2 = ld(__float_as_int(p23.x) + foff);
                if (g3) u3 = ld(__float_as_int(p23.z) + foff);
                fmaN(u0, p01.y);
                if (g1) fmaN(u1, p01.w);
                if (g2) fmaN(u2, p23.y);
                if (g3) fmaN(u3, p23.w);
            }
        }
    };

    if (deg <= 64) {
        int e = start + lane;
        int s = 0; float w = 0.f;
        if (e < end) { s = src_sorted[e]; w = __expf(lrelu(asrc[s] + ad)); }
        float dsum = wave_sum_bcast(w);
        esw[wave][tpos] = make_float2(__int_as_float(s << SH), w * (1.0f / dsum));
        gather((deg + 3) >> 2);
    } else {
        float part = 0.f;
        for (int cs = start; cs < end; cs += 64) {
            int e = cs + lane;
            if (e < end) part += __expf(lrelu(asrc[src_sorted[e]] + ad));
        }
        float inv = 1.0f / wave_sum_bcast(part);
        for (int cs = start; cs < end; cs += 64) {
            int e = cs + lane;
            int s = 0; float w = 0.f;
            if (e < end) { s = src_sorted[e]; w = __expf(lrelu(asrc[s] + ad)) * inv; }
            esw[wave][tpos] = make_float2(__int_as_float(s << SH), w);
            gather((min(64, end - cs) + 3) >> 2);
        }
    }

    // reduce the 4 edge-subsets, redistribute to per-lane final feats
    if constexpr (MODE == 2) {
        *reinterpret_cast<f32x4*>(&red[wave][sub][(lane & 15) * 4]) =
            (f32x4){acc[0], acc[1], acc[2], acc[3]};
        float t = 0.f;
#pragma unroll
        for (int g = 0; g < 4; g++) t += red[wave][g][lane];
        if (lane < 40) outf[(size_t)node * 40 + lane] = t + bias[lane];
    } else {
        f32x4* dst = reinterpret_cast<f32x4*>(&red[wave][sub][(lane & 15) * 8]);
        if constexpr (MODE == 0) {
            dst[0] = (f32x4){(float)acch[0][0], (float)acch[0][1],
                             (float)acch[1][0], (float)acch[1][1]};
            dst[1] = (f32x4){(float)acch[2][0], (float)acch[2][1],
                             (float)acch[3][0], (float)acch[3][1]};
        } else {
            dst[0] = (f32x4){acc[0], acc[1], acc[2], acc[3]};
            dst[1] = (f32x4){acc[4], acc[5], acc[6], acc[7]};
        }
        f32x2 tsum = (f32x2){0.f, 0.f};
#pragma unroll
        for (int g = 0; g < 4; g++)
            tsum += *reinterpret_cast<const f32x2*>(&red[wave][g][lane * 2]);

        if constexpr (MODE == 0) {
            // epilogue: bias+BN+tanh, fp8-pair write, fused next-layer alphas
            float vals[2];
#pragma unroll
            for (int v = 0; v < 2; v++) {
                int f = lane * 2 + v;
                float val = tsum[v] + bias[f];
                float rs = rsqrtf(rvar[f] + BN_EPS);
                vals[v] = tanh_fast((val - rmean[f]) * rs * gamma[f] + beta[f]);
            }
            ohi[(size_t)node * 64 + lane] = pk_fp8(vals[0], vals[1]);
            float ps = vals[0] * wsn[lane * 2] + vals[1] * wsn[lane * 2 + 1];
            float pd = vals[0] * wdn[lane * 2] + vals[1] * wdn[lane * 2 + 1];
            ps = wave_sum63(ps);
            pd = wave_sum63(pd);
            if (lane == 63) { asrc_n[node] = ps; adst_n[node] = pd; }
        } else {
            // fragment-major bf16-hi write (next GEMM's A)
            const size_t CSTRIDE = (size_t)N_NODES * 32;
            unsigned w0 = (unsigned)f2bf(tsum[0]) | ((unsigned)f2bf(tsum[1]) << 16);
            size_t a = (size_t)(lane >> 4) * CSTRIDE + (size_t)node * 32 + ((lane * 2) & 31);
            *reinterpret_cast<unsigned*>(ohi + a) = w0;
        }
    }
}

// ---------------------------------------------------------------------------

static inline size_t align256(size_t x) { return (x + 255) & ~(size_t)255; }

extern "C" void kernel_launch(void* const* d_in, const int* in_sizes, int n_in,
                              void* d_out, int out_size, void* d_ws, size_t ws_size,
                              hipStream_t stream) {
    const float* x   = (const float*)d_in[0];
    const int* ei    = (const int*)d_in[1];
    const float* w1  = (const float*)d_in[2];
    const float* as1 = (const float*)d_in[3];
    const float* ad1 = (const float*)d_in[4];
    const float* b1  = (const float*)d_in[5];
    const float* g1  = (const float*)d_in[6];
    const float* be1 = (const float*)d_in[7];
    const float* rm1 = (const float*)d_in[8];
    const float* rv1 = (const float*)d_in[9];
    const float* w2  = (const float*)d_in[10];
    const float* as2 = (const float*)d_in[11];
    const float* ad2 = (const float*)d_in[12];
    const float* b2  = (const float*)d_in[13];
    const float* g2  = (const float*)d_in[14];
    const float* be2 = (const float*)d_in[15];
    const float* rm2 = (const float*)d_in[16];
    const float* rv2 = (const float*)d_in[17];
    const float* w3  = (const float*)d_in[18];
    const float* as3 = (const float*)d_in[19];
    const float* ad3 = (const float*)d_in[20];
    const float* b3  = (const float*)d_in[21];
    float* out = (float*)d_out;

    const size_t P128 = align256((size_t)N_NODES * 128 * 2);
    const size_t P256 = align256((size_t)N_NODES * 256 * 2);

    char* p = (char*)d_ws;
    // regA: o1fp8 (front quarter, dead after agg2) -> h3 f16 (front, ldh=64)
    char* regA = p; p += P256;
    // regB: CSR scratch (pairs/bh/totals/starts) -> h1 f16 (front, row-major)
    //       -> g2hi (front, fragment; live through gemm23_fused)
    char* regB = p; p += P256;
    unsigned short* o1p  = (unsigned short*)regA;   // fp8 pairs: N*64 u16
    unsigned short* h3h  = (unsigned short*)regA;   // f16, N*64 u16 (o1p dead)
    unsigned short* h1h  = (unsigned short*)regB;   // f16, N x 128
    unsigned short* g2hi = (unsigned short*)regB;
    // CSR scratch aliases regB front (dead before GEMM1 writes h1h)
    int* pairs  = (int*)regB;                                        // E ints
    int* bhist  = (int*)(regB + align256((size_t)TOT_EDGES * 4));    // NBA*NBKT
    int* totals = (int*)((char*)bhist + align256((size_t)NBA * NBKT * 4));
    int* starts = (int*)((char*)totals + align256((size_t)NBKT * 4)); // NBKT+1

    float* asrcA = (float*)p; p += align256((size_t)N_NODES * 4);
    float* adstA = (float*)p; p += align256((size_t)N_NODES * 4);
    float* asrcB = (float*)p; p += align256((size_t)N_NODES * 4);
    float* adstB = (float*)p; p += align256((size_t)N_NODES * 4);
    int* row_ptr   = (int*)p; p += align256((size_t)(N_NODES + 1) * 4);
    int* src_sorted = (int*)p; p += align256((size_t)TOT_EDGES * 4);
    unsigned short* w1th = (unsigned short*)p; p += align256(128 * 128 * 2);
    unsigned short* w1tl = (unsigned short*)p; p += align256(128 * 128 * 2);
    unsigned short* w2th = (unsigned short*)p; p += align256(256 * 128 * 2);
    unsigned short* w2tl = (unsigned short*)p; p += align256(256 * 128 * 2);
    unsigned short* w3th = (unsigned short*)p; p += align256(48 * 256 * 2);
    unsigned short* w3tl = (unsigned short*)p; p += align256(48 * 256 * 2);
    unsigned short* ab1h = (unsigned short*)p; p += align256(16 * 128 * 2);
    unsigned short* ab1l = (unsigned short*)p; p += align256(16 * 128 * 2);
    unsigned short* ab3h = (unsigned short*)p; p += align256(16 * 256 * 2);
    unsigned short* ab3l = (unsigned short*)p; p += align256(16 * 256 * 2);
    float* ws2f = (float*)p; p += align256(128 * 4);
    float* wd2f = (float*)p; p += align256(128 * 4);
    float* bn2S = (float*)p; p += align256(256 * 4);
    float* bn2T = (float*)p; p += align256(256 * 4);

    const int WTOT = 128 * 128 + 256 * 128 + 48 * 256 + 2048 + 4096 + 256 + 256;

    wprep_all<<<(WTOT + 255) / 256, 256, 0, stream>>>(
        w1, w2, w3, as1, ad1, as2, ad2, as3, ad3,
        b2, g2, be2, rm2, rv2,
        w1th, w1tl, w2th, w2tl, w3th, w3tl,
        ab1h, ab1l, ab3h, ab3l, ws2f, wd2f, bn2S, bn2T);

    // CSR build: two-level LDS counting sort (no global atomics)
    csr_hist<<<NBA, 256, 0, stream>>>(ei, bhist);
    csr_scan_blocks<<<NBKT, 512, 0, stream>>>(bhist, totals);
    csr_scan_buckets<<<1, 512, 0, stream>>>(totals, starts);
    csr_scatter<<<NBA, 256, 0, stream>>>(ei, bhist, starts, pairs);
    csr_build<<<NBKT, 256, 0, stream>>>(pairs, starts, row_ptr, src_sorted);

    const int NWB = (N_NODES + 3) / 4;
    const int G64 = (N_NODES + 63) / 64;

    // --- Layer 1: h1 = x@w1 (+alpha1), A = x f32 DIRECT (inline split),
    //     C row-major f16; agg1(wide, f16-pk accum) -> o1 (fp8) ---
    mfma_gemm<128, 2, 1, 4, 128, true, true, false, false, true, true><<<G64, 256, 0, stream>>>(
        (const unsigned short*)x, nullptr, w1th, w1tl, ab1h, ab1l, h1h, 128,
        nullptr, nullptr, nullptr, nullptr, nullptr, asrcA, adstA, N_NODES);
    gat_agg_wide<0><<<NWB, 256, 0, stream>>>(
        h1h, asrcA, adstA, row_ptr, src_sorted,
        b1, g1, be1, rm1, rv1, ws2f, wd2f,
        o1p, nullptr, asrcB, adstB);

    // --- Layer 2 (commuted): g2 = S2(o1 fp8) -> fragment-major bf16-hi ---
    gat_agg_wide<1><<<NWB, 256, 0, stream>>>(
        o1p, asrcB, adstB, row_ptr, src_sorted,
        nullptr, nullptr, nullptr, nullptr, nullptr, nullptr, nullptr,
        g2hi, nullptr, nullptr, nullptr);

    // --- Layers 2+3 fused (v3 config): o2 = tanh(g2@w2*S+T) -> LDS ->
    //     h3 = o2@w3 (+alpha3); h3 overwrites o1p region (dead) ---
    gemm23_fused<<<G64, 512, 0, stream>>>(
        g2hi, w2th, w2tl, bn2S, bn2T,
        w3th, w3tl, ab3h, ab3l, h3h, asrcA, adstA, N_NODES);

    // --- Layer 3 aggregation -> out ---
    gat_agg_wide<2><<<NWB, 256, 0, stream>>>(
        h3h, asrcA, adstA, row_ptr, src_sorted,
        b3, nullptr, nullptr, nullptr, nullptr, nullptr, nullptr,
        nullptr, out, nullptr, nullptr);
}